// Round 1
// baseline (299.020 us; speedup 1.0000x reference)
//
#include <hip/hip_runtime.h>

// Involution2d fused, MFMA + sliding-window involution.
// Block = (batch, 8-row x 16-col tile), 256 threads / 4 waves, 2 blocks/CU.
// Phase 1: rT[p][o] = bf16(ReLU(BN(w_reduce @ x)))   via mfma 16x16x32 bf16
// Phase 2 per group: kernel-gen MFMA -> s_w[k][p] fp32; involution with
//   4 output px/lane (b128 weight + xh reads), 2 cg planes/lane.

typedef __attribute__((ext_vector_type(8))) short bf16x8;
typedef __attribute__((ext_vector_type(4))) float f32x4;

namespace {
constexpr int Cn = 256, Hn = 64, Wn = 64, HWn = 4096;
constexpr int Gn = 16, CGn = 16, CRn = 64;
constexpr int Kn = 7, PADn = 3, KKn = 49;
constexpr int TH = 8, TW = 16, TP = 128;   // tile pixels
constexpr int LD = 72, LDW = 36;           // bf16 row stride (64 + 8 pad) / dwords
constexpr int WLD = 132;                   // s_w fp32 row stride (128 px + 4 pad)
constexpr int XROW = 24, XPS = 344;        // xh row stride / plane stride (dwords)
constexpr int HR = 14, HC = 22;            // halo extent for 8x16 tile
}

__device__ __forceinline__ unsigned short bf16rne(float f) {
  unsigned u = __float_as_uint(f);
  u += 0x7fffu + ((u >> 16) & 1u);
  return (unsigned short)(u >> 16);
}
__device__ __forceinline__ unsigned packbf2(float a, float b) {
  return (unsigned)bf16rne(a) | ((unsigned)bf16rne(b) << 16);
}

__global__ __launch_bounds__(256, 2) void invol_fused(
    const float* __restrict__ x, const float* __restrict__ w_reduce,
    const float* __restrict__ w_span, const float* __restrict__ bn_gamma,
    const float* __restrict__ bn_beta, const float* __restrict__ bn_mean,
    const float* __restrict__ bn_var, float* __restrict__ out)
{
  __shared__ __align__(16) unsigned short s_rT[TP * LD];   // 18.4 KB, persists
  __shared__ __align__(16) unsigned short s_a [64 * LD];   // 9.2 KB: wr / w_span slice
  __shared__ __align__(16) float s_u[KKn * WLD];           // 25.9 KB: ph1 xT bf16 / ph2 s_w fp32
  __shared__ __align__(16) float s_xh[16 * XPS];           // 22.0 KB: 16 halo planes

  const int t = threadIdx.x;
  const int lane = t & 63, q = t >> 6;
  const int m16 = lane & 15, quad = lane >> 4;
  const int s = lane >> 5;                 // half of wave -> cg split
  const int slot = lane & 31;
  const int py = slot >> 2, px0 = (slot & 3) * 4;
  const int w0 = blockIdx.x * TW, h0 = blockIdx.y * TH;
  const int b = blockIdx.z;
  const long xbase = (long)b * Cn * HWn;

  // BN constants for this lane's phase-1 D rows (o = q*16 + quad*4 + r)
  float bsc[4], bsh[4];
  {
    int ob = q * 16 + quad * 4;
#pragma unroll
    for (int r = 0; r < 4; ++r) {
      float sc = bn_gamma[ob + r] * rsqrtf(bn_var[ob + r] + 1e-5f);
      bsc[r] = sc;
      bsh[r] = bn_beta[ob + r] - bn_mean[ob + r] * sc;
    }
  }

  // ---------------- Phase 1: rT = bf16(ReLU(BN(w_reduce @ x))) ----------------
  f32x4 pac[8];
#pragma unroll
  for (int pt = 0; pt < 8; ++pt) pac[pt] = (f32x4){0.f, 0.f, 0.f, 0.f};

  unsigned short* xT = (unsigned short*)s_u;  // [128 p][72] bf16

  for (int cc = 0; cc < Cn; cc += 64) {
    __syncthreads();
#pragma unroll
    for (int it = 0; it < 8; ++it) {        // s_a = w_reduce[o][cc..] bf16
      int idx = t + it * 256;
      int o = idx >> 5, cp = idx & 31;
      float2 v = *(const float2*)(w_reduce + o * Cn + cc + cp * 2);
      ((unsigned*)s_a)[o * LDW + cp] = packbf2(v.x, v.y);
    }
#pragma unroll
    for (int it = 0; it < 16; ++it) {       // xT[p][c] bf16 (2 ch packed)
      int idx = t + it * 256;
      int pp = idx & 127, cp = idx >> 7;
      const float* gp = x + xbase + (long)(cc + cp * 2) * HWn
                        + (h0 + (pp >> 4)) * Wn + (w0 + (pp & 15));
      ((unsigned*)xT)[pp * LDW + cp] = packbf2(gp[0], gp[HWn]);
    }
    __syncthreads();
#pragma unroll
    for (int ks = 0; ks < 2; ++ks) {
      bf16x8 af = *(const bf16x8*)(s_a + (q * 16 + m16) * LD + ks * 32 + quad * 8);
#pragma unroll
      for (int pt = 0; pt < 8; ++pt) {
        bf16x8 bf = *(const bf16x8*)(xT + (pt * 16 + m16) * LD + ks * 32 + quad * 8);
        pac[pt] = __builtin_amdgcn_mfma_f32_16x16x32_bf16(af, bf, pac[pt], 0, 0, 0);
      }
    }
  }
  // epilogue: BN+ReLU -> rT[p][o] bf16 pairs
#pragma unroll
  for (int pt = 0; pt < 8; ++pt) {
    int pp = pt * 16 + m16;
    float v0 = fmaxf(fmaf(pac[pt][0], bsc[0], bsh[0]), 0.f);
    float v1 = fmaxf(fmaf(pac[pt][1], bsc[1], bsh[1]), 0.f);
    float v2 = fmaxf(fmaf(pac[pt][2], bsc[2], bsh[2]), 0.f);
    float v3 = fmaxf(fmaf(pac[pt][3], bsc[3], bsh[3]), 0.f);
    ((unsigned*)s_rT)[pp * LDW + q * 8 + quad * 2 + 0] = packbf2(v0, v1);
    ((unsigned*)s_rT)[pp * LDW + q * 8 + quad * 2 + 1] = packbf2(v2, v3);
  }

  // ---------------- Phase 2 ----------------
  float* s_w = s_u;                          // [49 k][132] fp32
  const int cgA = q + 4 * s;                 // this lane's 2 cg planes
  const int cgB = cgA + 8;
  const float* plA = s_xh + cgA * XPS;
  const float* plB = s_xh + cgB * XPS;
  const long opix = (h0 + py) * Wn + (w0 + px0);

  for (int g = 0; g < Gn; ++g) {
    __syncthreads();  // prior reads of s_a/s_u/s_xh done
#pragma unroll
    for (int it = 0; it < 8; ++it) {        // s_a = w_span[g] slice [k][o] bf16
      int idx = t + it * 256;
      int k = idx >> 5, op = idx & 31;
      unsigned pv = 0u;
      if (k < KKn) {
        float2 v = *(const float2*)(w_span + (long)(g * KKn + k) * CRn + op * 2);
        pv = packbf2(v.x, v.y);
      }
      ((unsigned*)s_a)[k * LDW + op] = pv;
    }
    for (int idx = t; idx < 16 * 336; idx += 256) {  // 16 halo planes
      int pl = idx / 336, rem = idx - pl * 336;
      int iy = rem / XROW, ix = rem - iy * XROW;     // ix 22,23: harmless pad
      int gy = h0 + iy - PADn, gx = w0 + ix - PADn;
      float v = 0.f;
      if ((unsigned)gy < (unsigned)Hn && (unsigned)gx < (unsigned)Wn)
        v = x[xbase + (long)(g * CGn + pl) * HWn + gy * Wn + gx];
      s_xh[pl * XPS + iy * XROW + ix] = v;
    }
    __syncthreads();

    // kernel-gen: wave q -> k-tile q; D[k][p] = w_span @ r
    f32x4 wac[8];
#pragma unroll
    for (int pt = 0; pt < 8; ++pt) wac[pt] = (f32x4){0.f, 0.f, 0.f, 0.f};
#pragma unroll
    for (int ks = 0; ks < 2; ++ks) {
      bf16x8 af = *(const bf16x8*)(s_a + (q * 16 + m16) * LD + ks * 32 + quad * 8);
#pragma unroll
      for (int pt = 0; pt < 8; ++pt) {
        bf16x8 bf = *(const bf16x8*)(s_rT + (pt * 16 + m16) * LD + ks * 32 + quad * 8);
        wac[pt] = __builtin_amdgcn_mfma_f32_16x16x32_bf16(af, bf, wac[pt], 0, 0, 0);
      }
    }
    {
      int kb = q * 16 + quad * 4;
#pragma unroll
      for (int r = 0; r < 4; ++r) {
        if (kb + r < KKn) {
#pragma unroll
          for (int pt = 0; pt < 8; ++pt)
            s_w[(kb + r) * WLD + pt * 16 + m16] = wac[pt][r];
        }
      }
    }
    __syncthreads();

    // involution: 4 px/lane sliding window, 2 cg planes
    f32x4 a0 = (f32x4){0.f, 0.f, 0.f, 0.f};
    f32x4 a1 = (f32x4){0.f, 0.f, 0.f, 0.f};
#pragma unroll 1
    for (int i = 0; i < Kn; ++i) {
      f32x4 wr_[7];
#pragma unroll
      for (int jx = 0; jx < Kn; ++jx)
        wr_[jx] = *(const f32x4*)(s_w + (i * Kn + jx) * WLD + py * 16 + px0);
      const float* rA = plA + (py + i) * XROW + px0;
      const float* rB = plB + (py + i) * XROW + px0;
      f32x4 xa0 = *(const f32x4*)rA, xa1 = *(const f32x4*)(rA + 4), xa2 = *(const f32x4*)(rA + 8);
      f32x4 xb0 = *(const f32x4*)rB, xb1 = *(const f32x4*)(rB + 4), xb2 = *(const f32x4*)(rB + 8);
      float xa[12] = {xa0[0], xa0[1], xa0[2], xa0[3], xa1[0], xa1[1], xa1[2], xa1[3],
                      xa2[0], xa2[1], xa2[2], xa2[3]};
      float xb[12] = {xb0[0], xb0[1], xb0[2], xb0[3], xb1[0], xb1[1], xb1[2], xb1[3],
                      xb2[0], xb2[1], xb2[2], xb2[3]};
#pragma unroll
      for (int jx = 0; jx < Kn; ++jx) {
#pragma unroll
        for (int j = 0; j < 4; ++j) {
          a0[j] = fmaf(wr_[jx][j], xa[jx + j], a0[j]);
          a1[j] = fmaf(wr_[jx][j], xb[jx + j], a1[j]);
        }
      }
    }
    float* ob = out + xbase + (long)(g * CGn) * HWn + opix;
    *(f32x4*)(ob + (long)cgA * HWn) = a0;
    *(f32x4*)(ob + (long)cgB * HWn) = a1;
  }
}

extern "C" void kernel_launch(void* const* d_in, const int* in_sizes, int n_in,
                              void* d_out, int out_size, void* d_ws, size_t ws_size,
                              hipStream_t stream) {
  const float* x        = (const float*)d_in[0];
  const float* w_reduce = (const float*)d_in[1];
  const float* w_span   = (const float*)d_in[2];
  const float* bn_gamma = (const float*)d_in[3];
  const float* bn_beta  = (const float*)d_in[4];
  const float* bn_mean  = (const float*)d_in[5];
  const float* bn_var   = (const float*)d_in[6];
  float* outp = (float*)d_out;

  dim3 grid(Wn / TW, Hn / TH, 16);  // 4 x 8 x 16 = 512 blocks, 2/CU
  invol_fused<<<grid, 256, 0, stream>>>(x, w_reduce, w_span, bn_gamma,
                                        bn_beta, bn_mean, bn_var, outp);
}

// Round 2
// 194.373 us; speedup vs baseline: 1.5384x; 1.5384x over previous
//
#include <hip/hip_runtime.h>

// Involution2d fused, MFMA + sliding-window involution.
// Block = (batch, 8-row x 16-col tile), 256 threads / 4 waves, 2 blocks/CU.
// Phase 1: rT[p][o] = bf16(ReLU(BN(w_reduce @ x)))   via mfma 16x16x32 bf16
// Phase 2 per group: kernel-gen MFMA -> s_w[k][p] fp32; involution with
//   4 output px/lane (b128 weight + xh reads), 2 cg planes/lane.
// R2: lgkm-only barriers (keep global loads in flight across barriers) +
//     register-staged prefetch one iteration ahead (phase-1 cc loop and
//     phase-2 group loop) so halo/weight HBM latency hides under MFMA +
//     involution compute. XPS 344->348 to decouple half-wave bank sets.

typedef __attribute__((ext_vector_type(8))) short bf16x8;
typedef __attribute__((ext_vector_type(4))) float f32x4;

namespace {
constexpr int Cn = 256, Hn = 64, Wn = 64, HWn = 4096;
constexpr int Gn = 16, CGn = 16, CRn = 64;
constexpr int Kn = 7, PADn = 3, KKn = 49;
constexpr int TH = 8, TW = 16, TP = 128;   // tile pixels
constexpr int LD = 72, LDW = 36;           // bf16 row stride (64 + 8 pad) / dwords
constexpr int WLD = 132;                   // s_w fp32 row stride (128 px + 4 pad)
constexpr int XROW = 24, XPS = 348;        // xh row stride / plane stride (dwords)
}

__device__ __forceinline__ unsigned short bf16rne(float f) {
  unsigned u = __float_as_uint(f);
  u += 0x7fffu + ((u >> 16) & 1u);
  return (unsigned short)(u >> 16);
}
__device__ __forceinline__ unsigned packbf2(float a, float b) {
  return (unsigned)bf16rne(a) | ((unsigned)bf16rne(b) << 16);
}

// lgkm-only barrier: LDS producer/consumer ordering WITHOUT draining vmcnt,
// so register-staged global prefetch loads stay in flight across it.
__device__ __forceinline__ void bar_lgkm() {
  asm volatile("s_waitcnt lgkmcnt(0)" ::: "memory");
  __builtin_amdgcn_s_barrier();
}

__global__ __launch_bounds__(256, 2) void invol_fused(
    const float* __restrict__ x, const float* __restrict__ w_reduce,
    const float* __restrict__ w_span, const float* __restrict__ bn_gamma,
    const float* __restrict__ bn_beta, const float* __restrict__ bn_mean,
    const float* __restrict__ bn_var, float* __restrict__ out)
{
  __shared__ __align__(16) unsigned short s_rT[TP * LD];   // 18.4 KB, persists
  __shared__ __align__(16) unsigned short s_a [64 * LD];   // 9.2 KB: wr / w_span slice
  __shared__ __align__(16) float s_u[KKn * WLD];           // 25.9 KB: ph1 xT bf16 / ph2 s_w fp32
  __shared__ __align__(16) float s_xh[16 * XPS];           // 22.3 KB: 16 halo planes

  const int t = threadIdx.x;
  const int lane = t & 63, q = t >> 6;
  const int m16 = lane & 15, quad = lane >> 4;
  const int s = lane >> 5;                 // half of wave -> cg split
  const int slot = lane & 31;
  const int py = slot >> 2, px0 = (slot & 3) * 4;
  const int w0 = blockIdx.x * TW, h0 = blockIdx.y * TH;
  const int b = blockIdx.z;
  const long xbase = (long)b * Cn * HWn;

  // BN constants for this lane's phase-1 D rows (o = q*16 + quad*4 + r)
  float bsc[4], bsh[4];
  {
    int ob = q * 16 + quad * 4;
#pragma unroll
    for (int r = 0; r < 4; ++r) {
      float sc = bn_gamma[ob + r] * rsqrtf(bn_var[ob + r] + 1e-5f);
      bsc[r] = sc;
      bsh[r] = bn_beta[ob + r] - bn_mean[ob + r] * sc;
    }
  }

  // ---------------- Phase 1: rT = bf16(ReLU(BN(w_reduce @ x))) ----------------
  f32x4 pac[8];
#pragma unroll
  for (int pt = 0; pt < 8; ++pt) pac[pt] = (f32x4){0.f, 0.f, 0.f, 0.f};

  unsigned short* xT = (unsigned short*)s_u;  // [128 p][72] bf16

  // staging registers, phase 1 (issued one cc-step ahead)
  float2 pwr[8];
  float pxa[16], pxb[16];
  auto issue_cc = [&](int cc) {
#pragma unroll
    for (int it = 0; it < 8; ++it) {
      int idx = t + it * 256;
      int o = idx >> 5, cp = idx & 31;
      pwr[it] = *(const float2*)(w_reduce + o * Cn + cc + cp * 2);
    }
#pragma unroll
    for (int it = 0; it < 16; ++it) {
      int idx = t + it * 256;
      int pp = idx & 127, cp = idx >> 7;
      const float* gp = x + xbase + (long)(cc + cp * 2) * HWn
                        + (h0 + (pp >> 4)) * Wn + (w0 + (pp & 15));
      pxa[it] = gp[0];
      pxb[it] = gp[HWn];
    }
  };

  issue_cc(0);
  for (int cc = 0; cc < Cn; cc += 64) {
    bar_lgkm();
#pragma unroll
    for (int it = 0; it < 8; ++it) {        // s_a = w_reduce[o][cc..] bf16
      int idx = t + it * 256;
      int o = idx >> 5, cp = idx & 31;
      ((unsigned*)s_a)[o * LDW + cp] = packbf2(pwr[it].x, pwr[it].y);
    }
#pragma unroll
    for (int it = 0; it < 16; ++it) {       // xT[p][c] bf16 (2 ch packed)
      int idx = t + it * 256;
      int pp = idx & 127, cp = idx >> 7;
      ((unsigned*)xT)[pp * LDW + cp] = packbf2(pxa[it], pxb[it]);
    }
    if (cc + 64 < Cn) issue_cc(cc + 64);    // prefetch next cc-step (flies over barriers)
    bar_lgkm();
#pragma unroll
    for (int ks = 0; ks < 2; ++ks) {
      bf16x8 af = *(const bf16x8*)(s_a + (q * 16 + m16) * LD + ks * 32 + quad * 8);
#pragma unroll
      for (int pt = 0; pt < 8; ++pt) {
        bf16x8 bf = *(const bf16x8*)(xT + (pt * 16 + m16) * LD + ks * 32 + quad * 8);
        pac[pt] = __builtin_amdgcn_mfma_f32_16x16x32_bf16(af, bf, pac[pt], 0, 0, 0);
      }
    }
  }

  // staging registers, phase 2 (issued one group ahead)
  float2 pw[8];
  float ph[21];
  auto issue_g = [&](int g) {
#pragma unroll
    for (int it = 0; it < 8; ++it) {        // w_span[g] slice
      int idx = t + it * 256;
      int k = idx >> 5, op = idx & 31;
      if (k < KKn)
        pw[it] = *(const float2*)(w_span + (long)(g * KKn + k) * CRn + op * 2);
    }
#pragma unroll
    for (int it = 0; it < 21; ++it) {       // 16 halo planes (16*336 = 21*256)
      int idx = t + it * 256;
      int pl = idx / 336, rem = idx - pl * 336;
      int iy = rem / XROW, ix = rem - iy * XROW;   // ix 22,23: harmless pad
      int gy = h0 + iy - PADn, gx = w0 + ix - PADn;
      float v = 0.f;
      if ((unsigned)gy < (unsigned)Hn && (unsigned)gx < (unsigned)Wn)
        v = x[xbase + (long)(g * CGn + pl) * HWn + gy * Wn + gx];
      ph[it] = v;
    }
  };

  issue_g(0);  // overlaps epilogue + first barriers

  // epilogue: BN+ReLU -> rT[p][o] bf16 pairs
#pragma unroll
  for (int pt = 0; pt < 8; ++pt) {
    int pp = pt * 16 + m16;
    float v0 = fmaxf(fmaf(pac[pt][0], bsc[0], bsh[0]), 0.f);
    float v1 = fmaxf(fmaf(pac[pt][1], bsc[1], bsh[1]), 0.f);
    float v2 = fmaxf(fmaf(pac[pt][2], bsc[2], bsh[2]), 0.f);
    float v3 = fmaxf(fmaf(pac[pt][3], bsc[3], bsh[3]), 0.f);
    ((unsigned*)s_rT)[pp * LDW + q * 8 + quad * 2 + 0] = packbf2(v0, v1);
    ((unsigned*)s_rT)[pp * LDW + q * 8 + quad * 2 + 1] = packbf2(v2, v3);
  }

  // ---------------- Phase 2 ----------------
  float* s_w = s_u;                          // [49 k][132] fp32
  const int cgA = q + 4 * s;                 // this lane's 2 cg planes
  const int cgB = cgA + 8;
  const float* plA = s_xh + cgA * XPS;
  const float* plB = s_xh + cgB * XPS;
  const long opix = (h0 + py) * Wn + (w0 + px0);

  for (int g = 0; g < Gn; ++g) {
    bar_lgkm();  // prior reads of s_a/s_u/s_xh done (vmcnt stays in flight)
#pragma unroll
    for (int it = 0; it < 8; ++it) {        // s_a = w_span[g] slice [k][o] bf16
      int idx = t + it * 256;
      int k = idx >> 5, op = idx & 31;
      unsigned pv = (k < KKn) ? packbf2(pw[it].x, pw[it].y) : 0u;
      ((unsigned*)s_a)[k * LDW + op] = pv;
    }
#pragma unroll
    for (int it = 0; it < 21; ++it) {       // 16 halo planes from staged regs
      int idx = t + it * 256;
      int pl = idx / 336, rem = idx - pl * 336;
      int iy = rem / XROW, ix = rem - iy * XROW;
      s_xh[pl * XPS + iy * XROW + ix] = ph[it];
    }
    if (g + 1 < Gn) issue_g(g + 1);         // prefetch next group (covers MFMA+involution)
    bar_lgkm();

    // kernel-gen: wave q -> k-tile q; D[k][p] = w_span @ r
    f32x4 wac[8];
#pragma unroll
    for (int pt = 0; pt < 8; ++pt) wac[pt] = (f32x4){0.f, 0.f, 0.f, 0.f};
#pragma unroll
    for (int ks = 0; ks < 2; ++ks) {
      bf16x8 af = *(const bf16x8*)(s_a + (q * 16 + m16) * LD + ks * 32 + quad * 8);
#pragma unroll
      for (int pt = 0; pt < 8; ++pt) {
        bf16x8 bf = *(const bf16x8*)(s_rT + (pt * 16 + m16) * LD + ks * 32 + quad * 8);
        wac[pt] = __builtin_amdgcn_mfma_f32_16x16x32_bf16(af, bf, wac[pt], 0, 0, 0);
      }
    }
    {
      int kb = q * 16 + quad * 4;
#pragma unroll
      for (int r = 0; r < 4; ++r) {
        if (kb + r < KKn) {
#pragma unroll
          for (int pt = 0; pt < 8; ++pt)
            s_w[(kb + r) * WLD + pt * 16 + m16] = wac[pt][r];
        }
      }
    }
    bar_lgkm();

    // involution: 4 px/lane sliding window, 2 cg planes
    f32x4 a0 = (f32x4){0.f, 0.f, 0.f, 0.f};
    f32x4 a1 = (f32x4){0.f, 0.f, 0.f, 0.f};
#pragma unroll 1
    for (int i = 0; i < Kn; ++i) {
      f32x4 wr_[7];
#pragma unroll
      for (int jx = 0; jx < Kn; ++jx)
        wr_[jx] = *(const f32x4*)(s_w + (i * Kn + jx) * WLD + py * 16 + px0);
      const float* rA = plA + (py + i) * XROW + px0;
      const float* rB = plB + (py + i) * XROW + px0;
      f32x4 xa0 = *(const f32x4*)rA, xa1 = *(const f32x4*)(rA + 4), xa2 = *(const f32x4*)(rA + 8);
      f32x4 xb0 = *(const f32x4*)rB, xb1 = *(const f32x4*)(rB + 4), xb2 = *(const f32x4*)(rB + 8);
      float xa[12] = {xa0[0], xa0[1], xa0[2], xa0[3], xa1[0], xa1[1], xa1[2], xa1[3],
                      xa2[0], xa2[1], xa2[2], xa2[3]};
      float xb[12] = {xb0[0], xb0[1], xb0[2], xb0[3], xb1[0], xb1[1], xb1[2], xb1[3],
                      xb2[0], xb2[1], xb2[2], xb2[3]};
#pragma unroll
      for (int jx = 0; jx < Kn; ++jx) {
#pragma unroll
        for (int j = 0; j < 4; ++j) {
          a0[j] = fmaf(wr_[jx][j], xa[jx + j], a0[j]);
          a1[j] = fmaf(wr_[jx][j], xb[jx + j], a1[j]);
        }
      }
    }
    float* ob = out + xbase + (long)(g * CGn) * HWn + opix;
    *(f32x4*)(ob + (long)cgA * HWn) = a0;
    *(f32x4*)(ob + (long)cgB * HWn) = a1;
  }
}

extern "C" void kernel_launch(void* const* d_in, const int* in_sizes, int n_in,
                              void* d_out, int out_size, void* d_ws, size_t ws_size,
                              hipStream_t stream) {
  const float* x        = (const float*)d_in[0];
  const float* w_reduce = (const float*)d_in[1];
  const float* w_span   = (const float*)d_in[2];
  const float* bn_gamma = (const float*)d_in[3];
  const float* bn_beta  = (const float*)d_in[4];
  const float* bn_mean  = (const float*)d_in[5];
  const float* bn_var   = (const float*)d_in[6];
  float* outp = (float*)d_out;

  dim3 grid(Wn / TW, Hn / TH, 16);  // 4 x 8 x 16 = 512 blocks, 2/CU
  invol_fused<<<grid, 256, 0, stream>>>(x, w_reduce, w_span, bn_gamma,
                                        bn_beta, bn_mean, bn_var, outp);
}